// Round 1
// baseline (72.135 us; speedup 1.0000x reference)
//
#include <hip/hip_runtime.h>

// VQ-VAE quantizer: x[32][64][64][64] f32 NCHW, embed[1024][64] f32
// out: z_q (8388608 f32, NCHW) ++ loss (1 f32)
// loss = 1.25 * mean((z_q - z)^2)

#define TOTAL_ELEMS 8388608
#define LOSS_SCALE (1.25f / 8388608.f)

typedef float  f32x4  __attribute__((ext_vector_type(4)));
typedef __bf16 bf16x8 __attribute__((ext_vector_type(8)));
typedef unsigned int u32x4 __attribute__((ext_vector_type(4)));

static __device__ __forceinline__ unsigned short f2bf(float f) {
    unsigned int u = __float_as_uint(f);
    u += 0x7FFFu + ((u >> 16) & 1u);   // round-to-nearest-even
    return (unsigned short)(u >> 16);
}

// ---- prep: embed f32 -> bf16 copy + row sumsq (e2) + zero loss slot ----
// grid 16 x 256: 4 threads per embed row
__global__ void vq_prep(const float* __restrict__ embed,
                        unsigned short* __restrict__ eb,
                        float* __restrict__ e2,
                        float* __restrict__ loss_slot) {
    int t   = blockIdx.x * 256 + threadIdx.x;   // 0..4095
    int row = t >> 2, qd = t & 3;
    const float* src = embed + row * 64 + qd * 16;
    float s = 0.f;
    unsigned short tmp[16];
#pragma unroll
    for (int i = 0; i < 4; i++) {
        f32x4 v = *(const f32x4*)(src + i * 4);
#pragma unroll
        for (int j = 0; j < 4; j++) {
            float f = v[j];
            s += f * f;
            tmp[i * 4 + j] = f2bf(f);
        }
    }
    u32x4 w0, w1;
#pragma unroll
    for (int i = 0; i < 4; i++) {
        w0[i] = (unsigned)tmp[2*i]     | ((unsigned)tmp[2*i+1] << 16);
        w1[i] = (unsigned)tmp[8+2*i]   | ((unsigned)tmp[8+2*i+1] << 16);
    }
    u32x4* dst = (u32x4*)(eb + row * 64 + qd * 16);
    dst[0] = w0; dst[1] = w1;
    // reduce sumsq across the 4 threads sharing a row (same wave)
    s += __shfl_xor(s, 1);
    s += __shfl_xor(s, 2);
    if (qd == 0) e2[row] = s;
    if (t == 0) *loss_slot = 0.f;
}

// ---- main fused kernel ----
// block = 256 threads = 4 waves; one block per (b,h): 64 positions (w) x 64 channels
// wave wv handles codes [wv*256, wv*256+256)
__global__ __launch_bounds__(256, 2) void vq_main(
    const float* __restrict__ x,
    const float* __restrict__ embed,            // f32, for exact gather
    const unsigned short* __restrict__ eb,      // bf16
    const float* __restrict__ e2,
    float* __restrict__ out,
    float* __restrict__ loss) {

    __shared__ unsigned short tile[64 * 64];    // [pos][k] bf16, XOR-swizzled, 8 KB
    __shared__ float wminv[4][64];
    __shared__ int   wmini[4][64];
    __shared__ int   idxf[64];
    __shared__ float lpart[4];

    const int t   = threadIdx.x;
    const int blk = blockIdx.x;                 // 0..2047
    const int b   = blk >> 6, h = blk & 63;
    const size_t base = (size_t)b * 262144 + (size_t)h * 64;  // x[b][0][h][0]

    // ---- stage Z tile into LDS (transpose [c][w] -> [w][c], f32 -> bf16) ----
    const int c = t & 63, q = t >> 6;           // q uniform within a wave
#pragma unroll
    for (int i = 0; i < 4; i++) {
        int w0 = q * 16 + i * 4;
        f32x4 v = *(const f32x4*)(x + base + (size_t)c * 4096 + w0);
#pragma unroll
        for (int j = 0; j < 4; j++) {
            int w = w0 + j;
            int byteoff = w * 128 + ((c * 2) ^ ((w & 7) << 4));
            *(unsigned short*)((char*)tile + byteoff) = f2bf(v[j]);
        }
    }
    __syncthreads();

    // ---- MFMA distance + argmin ----
    const int wv = t >> 6, lane = t & 63;
    const int l15 = lane & 15, lq = lane >> 4;  // lq: 0..3
    const int k0 = lq * 8;

    // B-frags: Z for 4 position-tiles x 2 K-halves (lane: pos=nt*16+l15, k=kh*32+k0..+7)
    bf16x8 bfr[4][2];
#pragma unroll
    for (int nt = 0; nt < 4; nt++) {
        int pos = nt * 16 + l15;
        int rb  = pos * 128;
        int sw  = (pos & 7) << 4;
        bfr[nt][0] = *(const bf16x8*)((const char*)tile + rb + ((k0 * 2) ^ sw));
        bfr[nt][1] = *(const bf16x8*)((const char*)tile + rb + ((64 + k0 * 2) ^ sw));
    }

    float minv[4];
    int   mini[4];
#pragma unroll
    for (int nt = 0; nt < 4; nt++) { minv[nt] = __builtin_inff(); mini[nt] = 0; }

    const int cb = wv * 256;
#pragma unroll
    for (int mt = 0; mt < 16; mt++) {
        // A-frags: embed rows (lane: code=cb+mt*16+l15, k=kh*32+k0..+7), L2-hot
        int mrow = cb + mt * 16 + l15;
        const bf16x8 a0 = *(const bf16x8*)(eb + mrow * 64 + k0);
        const bf16x8 a1 = *(const bf16x8*)(eb + mrow * 64 + 32 + k0);
        const f32x4  e2v = *(const f32x4*)(e2 + cb + mt * 16 + lq * 4);
#pragma unroll
        for (int nt = 0; nt < 4; nt++) {
            f32x4 acc = {0.f, 0.f, 0.f, 0.f};
            acc = __builtin_amdgcn_mfma_f32_16x16x32_bf16(a0, bfr[nt][0], acc, 0, 0, 0);
            acc = __builtin_amdgcn_mfma_f32_16x16x32_bf16(a1, bfr[nt][1], acc, 0, 0, 0);
            // D: col(l15)=pos-in-tile, row=(lq*4+r)=code-in-chunk
#pragma unroll
            for (int r = 0; r < 4; r++) {
                float d = fmaf(-2.f, acc[r], e2v[r]);
                int code = cb + mt * 16 + lq * 4 + r;
                bool lt = d < minv[nt];
                minv[nt] = lt ? d : minv[nt];
                mini[nt] = lt ? code : mini[nt];
            }
        }
    }

    // ---- wave-level argmin reduce (codes spread over lane^16, lane^32) ----
#pragma unroll
    for (int nt = 0; nt < 4; nt++) {
#pragma unroll
        for (int off = 16; off < 64; off <<= 1) {
            float ov = __shfl_xor(minv[nt], off);
            int   oi = __shfl_xor(mini[nt], off);
            if (ov < minv[nt] || (ov == minv[nt] && oi < mini[nt])) {
                minv[nt] = ov; mini[nt] = oi;
            }
        }
        if (lane < 16) {
            wminv[wv][nt * 16 + lane] = minv[nt];
            wmini[wv][nt * 16 + lane] = mini[nt];
        }
    }
    __syncthreads();

    // ---- cross-wave combine: thread t<64 -> final idx for position t ----
    if (t < 64) {
        float bv = wminv[0][t]; int bi = wmini[0][t];
#pragma unroll
        for (int w2 = 1; w2 < 4; w2++) {
            float ov = wminv[w2][t]; int oi = wmini[w2][t];
            if (ov < bv || (ov == bv && oi < bi)) { bv = ov; bi = oi; }
        }
        idxf[t] = bi;
    }
    __syncthreads();

    // ---- output: gather z_q (exact f32), write NCHW, loss partial ----
    float ls = 0.f;
#pragma unroll
    for (int i = 0; i < 4; i++) {
        int w0 = q * 16 + i * 4;
        const size_t off = base + (size_t)c * 4096 + w0;
        f32x4 xv = *(const f32x4*)(x + off);   // L1-hot re-read (exact z for loss)
        f32x4 ov;
#pragma unroll
        for (int j = 0; j < 4; j++) {
            int idx = idxf[w0 + j];            // uniform across wave -> coalesced gather
            float zq = embed[idx * 64 + c];
            ov[j] = zq;
            float d = zq - xv[j];
            ls += d * d;
        }
        *(f32x4*)(out + off) = ov;
    }

    // block-reduce loss, one atomic per block
#pragma unroll
    for (int off = 1; off < 64; off <<= 1) ls += __shfl_xor(ls, off);
    if (lane == 0) lpart[wv] = ls;
    __syncthreads();
    if (t == 0) {
        float s = lpart[0] + lpart[1] + lpart[2] + lpart[3];
        atomicAdd(loss, s * LOSS_SCALE);
    }
}

extern "C" void kernel_launch(void* const* d_in, const int* in_sizes, int n_in,
                              void* d_out, int out_size, void* d_ws, size_t ws_size,
                              hipStream_t stream) {
    const float* x     = (const float*)d_in[0];
    const float* embed = (const float*)d_in[1];
    unsigned short* eb = (unsigned short*)d_ws;               // 1024*64 bf16 = 128 KB
    float* e2          = (float*)((char*)d_ws + 131072);      // 1024 f32  = 4 KB
    float* out  = (float*)d_out;
    float* loss = out + TOTAL_ELEMS;

    vq_prep<<<16, 256, 0, stream>>>(embed, eb, e2, loss);
    vq_main<<<2048, 256, 0, stream>>>(x, embed, eb, e2, out, loss);
}